// Round 2
// baseline (577.057 us; speedup 1.0000x reference)
//
#include <hip/hip_runtime.h>
#include <stdint.h>

#define B_ 8
#define C_ 512
#define O_ 512
#define T_ 8192
#define KW 7
#define NW (O_*C_*KW)          // 1835008 weights
#define QT_ROWS (T_+32)        // qa row j holds t = j-4; rows 0..3 and 8196..8199 zeroed
#define MT 64
#define NT 256
#define BK 64                  // i8 channels per K-tile (64 B rows)
#define BROWS 272              // staged B rows per tile (256 + halo)

typedef __attribute__((ext_vector_type(4))) int i32x4;

// async global->LDS, 16B per lane; LDS dest is wave-uniform base + lane*16
__device__ __forceinline__ void gld16(const void* g, void* l) {
  __builtin_amdgcn_global_load_lds(
      (const __attribute__((address_space(1))) unsigned int*)g,
      (__attribute__((address_space(3))) unsigned int*)l, 16, 0, 0);
}

// ---- K1: per-(b,t) RMS + global absmax of normalized tensor ----------------
// block = 256 t x 512 c (c-split x4 over waves); float4 reads (16 B/lane)
__global__ __launch_bounds__(256) void k_rms(const float* __restrict__ x,
    const float* __restrict__ gamma, float* __restrict__ rms,
    unsigned* __restrict__ scale_bits)
{
  int tid = threadIdx.x, tl = tid & 63, cq = tid >> 6;
  int bt0 = blockIdx.x * 256;               // 256 | 8192 so no b-cross
  int b = bt0 >> 13, t = (bt0 & (T_ - 1)) + tl * 4;
  const float4* px = (const float4*)(x + ((size_t)b * C_ + cq * 128) * T_ + t);
  const float* pg = gamma + cq * 128;       // wave-uniform index -> scalar loads
  float4 ss = {0.f, 0.f, 0.f, 0.f};
  float4 mx = {0.f, 0.f, 0.f, 0.f};
  #pragma unroll 8
  for (int cc = 0; cc < 128; ++cc) {
    float4 v = px[(size_t)cc * (T_ / 4)];   // lanes consecutive -> 1 KB/wave-load
    float g = pg[cc];
    ss.x = fmaf(v.x, v.x, ss.x); ss.y = fmaf(v.y, v.y, ss.y);
    ss.z = fmaf(v.z, v.z, ss.z); ss.w = fmaf(v.w, v.w, ss.w);
    mx.x = fmaxf(mx.x, fabsf(v.x * g)); mx.y = fmaxf(mx.y, fabsf(v.y * g));
    mx.z = fmaxf(mx.z, fabsf(v.z * g)); mx.w = fmaxf(mx.w, fabsf(v.w * g));
  }
  __shared__ float4 s_ss[4][64];
  __shared__ float4 s_m[4][64];
  __shared__ unsigned sm;
  s_ss[cq][tl] = ss; s_m[cq][tl] = mx;
  if (tid == 0) sm = 0u;
  __syncthreads();
  if (cq == 0) {
    float4 a = s_ss[0][tl], b4 = s_ss[1][tl], c4 = s_ss[2][tl], d4 = s_ss[3][tl];
    float4 r;
    r.x = 1.0f / sqrtf((a.x + b4.x + c4.x + d4.x) * (1.0f / 512.0f) + 1e-6f);
    r.y = 1.0f / sqrtf((a.y + b4.y + c4.y + d4.y) * (1.0f / 512.0f) + 1e-6f);
    r.z = 1.0f / sqrtf((a.z + b4.z + c4.z + d4.z) * (1.0f / 512.0f) + 1e-6f);
    r.w = 1.0f / sqrtf((a.w + b4.w + c4.w + d4.w) * (1.0f / 512.0f) + 1e-6f);
    ((float4*)rms)[blockIdx.x * 64 + tl] = r;
    float4 m0 = s_m[0][tl], m1 = s_m[1][tl], m2 = s_m[2][tl], m3 = s_m[3][tl];
    float mm = fmaxf(fmaxf(fmaxf(m0.x, m1.x), fmaxf(m2.x, m3.x)) * r.x,
              fmaxf(fmaxf(fmaxf(m0.y, m1.y), fmaxf(m2.y, m3.y)) * r.y,
              fmaxf(fmaxf(fmaxf(m0.z, m1.z), fmaxf(m2.z, m3.z)) * r.z,
                    fmaxf(fmaxf(m0.w, m1.w), fmaxf(m2.w, m3.w)) * r.w)));
    atomicMax(&sm, __float_as_uint(mm));    // candidates >=0 -> uint order ok
  }
  __syncthreads();
  if (tid == 0) atomicMax(scale_bits, sm);
}

// ---- K2a: sum |w| (+ fused qa halo zeroing in first 32 blocks) -------------
__global__ __launch_bounds__(256) void k_wsum(const float* __restrict__ w,
    double* __restrict__ wsum, char* __restrict__ qa)
{
  int tid = threadIdx.x;
  if (blockIdx.x < 32) {                    // zero t-halo rows of qa (4 B writes)
    int g4 = blockIdx.x * 256 + tid;        // 0..8191 -> 32 KB
    int b = g4 >> 10;
    int idx = (g4 & 1023) * 4;              // byte idx within b's 8 halo rows
    int rr = idx >> 9, c = idx & 511;
    int row = (rr < 4) ? rr : (T_ + rr);    // rows 0..3 and 8196..8199
    *(unsigned*)&qa[((size_t)b * QT_ROWS + row) * C_ + c] = 0u;
  }
  size_t g = (size_t)blockIdx.x * 256 + tid;
  float s = 0.f;
  for (size_t i = g; i < (size_t)NW; i += (size_t)gridDim.x * 256)
    s += fabsf(w[i]);
  __shared__ float red[256];
  red[tid] = s; __syncthreads();
  for (int h = 128; h > 0; h >>= 1) {
    if (tid < h) red[tid] += red[tid + h];
    __syncthreads();
  }
  if (tid == 0) atomicAdd(wsum, (double)red[0]);
}

// ---- K2b: ternary-quantize weights into wqi[k][o][c] (int8 {-1,0,1}) -------
__global__ __launch_bounds__(256) void k_wq(const float* __restrict__ w,
    const double* __restrict__ wsum, char* __restrict__ wqi)
{
  int g = blockIdx.x * 256 + threadIdx.x;   // g = o*C_ + c
  float wsc = fmaxf((float)(*wsum * (1.0 / (double)NW)), 1e-4f);
  const float* pw = w + (size_t)g * KW;
  #pragma unroll
  for (int kk = 0; kk < KW; ++kk) {
    float q = rintf(fminf(fmaxf(pw[kk] / wsc, -1.f), 1.f));
    wqi[(size_t)kk * (O_ * C_) + g] = (char)(int)q;
  }
}

// ---- K3: quantize activations + transpose to qa[b][t+4][c] (int8) ----------
__global__ __launch_bounds__(256) void k_quant(const float* __restrict__ x,
    const float* __restrict__ gamma, const float* __restrict__ rms,
    const unsigned* __restrict__ scale_bits, char* __restrict__ qa)
{
  __shared__ float tile[64][65];            // +1 pad: conflict-free transpose
  int tid = threadIdx.x;
  int tt0 = blockIdx.x * 64;
  int c0  = blockIdx.y * 64;
  int b   = blockIdx.z;
  int tl = tid & 63;
  int q4 = tid >> 6;
  float qmul = 127.0f / fmaxf(__uint_as_float(*scale_bits), 1e-5f);
  const float* px = x + ((size_t)b * C_ + c0) * T_ + tt0;
  float rr = rms[b * T_ + tt0 + tl];
  #pragma unroll
  for (int cc = q4; cc < 64; cc += 4) {     // read coalesced along t
    float v = px[(size_t)cc * T_ + tl];
    float xn = (v * rr) * gamma[c0 + cc];
    tile[cc][tl] = rintf(fminf(fmaxf(xn * qmul, -128.f), 127.f));
  }
  __syncthreads();
  // pack 4 consecutive c into a dword; 4 t-rows per thread
  int c4 = (tid & 15) * 4, tb = tid >> 4;
  char* pq = qa + ((size_t)b * QT_ROWS + (tt0 + 4)) * C_ + c0;
  #pragma unroll
  for (int it = 0; it < 4; ++it) {
    int t2 = tb + it * 16;
    unsigned u = ((unsigned)(unsigned char)(char)(int)tile[c4 + 0][t2])
               | ((unsigned)(unsigned char)(char)(int)tile[c4 + 1][t2] << 8)
               | ((unsigned)(unsigned char)(char)(int)tile[c4 + 2][t2] << 16)
               | ((unsigned)(unsigned char)(char)(int)tile[c4 + 3][t2] << 24);
    *(unsigned*)&pq[(size_t)t2 * C_ + c4] = u;
  }
}

// ---- K4: conv as i8 MFMA GEMM (exact): out = alpha * sum_{k,c} Wk[o,c]*q[c,t+k-3]
// MT=64 x NT=256. v2: 2-phase pipeline —
//   * B (activations) double-buffered in LDS: stage c0+1 BEFORE computing c0;
//     single __syncthreads per c0 iter (its vmcnt drain lands after the whole
//     MFMA phase, so staging latency is hidden).
//   * A (ternary weights, 1.8 MB, L2-resident) loaded global->VGPR directly,
//     software-pipelined one tap ahead (a_cur/a_nxt). No A LDS, no A barriers.
__global__ __launch_bounds__(256, 3) void k_conv(
    const char* __restrict__ wqi,            // [KW][O_][C_] int8
    const char* __restrict__ qa,             // [B_][QT_ROWS][C_] int8 (row = t+4)
    float* __restrict__ out,
    const unsigned* __restrict__ scale_bits,
    const double* __restrict__ wsum)
{
  __shared__ __attribute__((aligned(16))) char lB[2][BROWS * BK];  // 2 x 17 KB
  int tid = threadIdx.x;
  int wave = tid >> 6, lane = tid & 63;
  int quad = lane >> 4, l16 = lane & 15;
  int lrow = lane >> 2;                      // staging: 16 rows x 4 chunks / instr
  int dch = ((lane & 3) - (lane >> 3)) & 3;  // swizzled data chunk for this lane
  int t0 = blockIdx.x * NT;
  int o0 = blockIdx.y * MT;
  int b  = blockIdx.z;

  const char* qa_b = qa + (size_t)b * QT_ROWS * C_;
  // per-lane A base: row (o0+l16), col (quad*16); natural layout, no swizzle
  const char* wA = wqi + (size_t)(o0 + l16) * C_ + quad * 16;

  i32x4 acc[4][4] = {};
  i32x4 a_cur[4], a_nxt[4] = {};

  // stage B for tile c0: qa rows t0..t0+271 (t = t0-4 .. t0+267); 17 gld16/block
  auto stageB = [&](int c0, char* dst) {
    for (int i = wave; i < 17; i += 4) {
      const char* gB = qa_b + (size_t)(t0 + i * 16 + lrow) * C_ + (c0 + dch * 16);
      gld16(gB, dst + i * 1024 + lane * 16);
    }
  };
  // load the 4 A fragments for tap k, channel tile c0 (16 B/lane, L2-resident)
  auto loadA = [&](i32x4* af, int k, int c0) {
    #pragma unroll
    for (int mt = 0; mt < 4; ++mt)
      af[mt] = *(const i32x4*)&wA[(size_t)(k * O_ + mt * 16) * C_ + c0];
  };

  // prologue: stage B(c0=0), prefetch A(k=0, c0=0)
  stageB(0, lB[0]);
  loadA(a_cur, 0, 0);
  __syncthreads();                           // drains vmcnt: lB[0] ready

  int cur = 0;
  for (int c0 = 0; c0 < C_; c0 += BK) {
    if (c0 + BK < C_) stageB(c0 + BK, lB[cur ^ 1]);   // in flight across MFMA phase
    const char* rb = lB[cur];
    #pragma unroll
    for (int k = 0; k < KW; ++k) {
      // prefetch next tap's A (or first tap of next c0) one step ahead
      if (k < KW - 1)            loadA(a_nxt, k + 1, c0);
      else if (c0 + BK < C_)     loadA(a_nxt, 0, c0 + BK);
      int sft = k + 1;                       // tap shift as LDS row offset
      i32x4 bf[4];
      #pragma unroll
      for (int nt = 0; nt < 4; ++nt) {      // B^T[t][c]: 16 contiguous c per lane
        int r = wave * 64 + nt * 16 + l16 + sft;
        bf[nt] = *(const i32x4*)
            &rb[r * BK + (((quad + (r >> 1)) & 3) * 16)];
      }
      #pragma unroll
      for (int mt = 0; mt < 4; ++mt)
        #pragma unroll
        for (int nt = 0; nt < 4; ++nt)
          acc[mt][nt] = __builtin_amdgcn_mfma_i32_16x16x64_i8(
              a_cur[mt], bf[nt], acc[mt][nt], 0, 0, 0);
      #pragma unroll
      for (int mt = 0; mt < 4; ++mt) a_cur[mt] = a_nxt[mt];  // SSA rotate
    }
    __syncthreads();   // waves done reading lB[cur]; lB[cur^1] staging drained
    cur ^= 1;
  }
  // epilogue: dequant scale. C/D layout: col=lane&15, row=quad*4+reg
  float sc  = fmaxf(__uint_as_float(*scale_bits), 1e-5f);
  float wsc = fmaxf((float)(*wsum * (1.0 / (double)NW)), 1e-4f);
  float alpha = sc * (1.0f / 127.0f) * wsc;
  #pragma unroll
  for (int mt = 0; mt < 4; ++mt) {
    int o = o0 + mt * 16 + quad * 4;
    #pragma unroll
    for (int nt = 0; nt < 4; ++nt) {
      int t = t0 + wave * 64 + nt * 16 + l16;
      float* po = out + ((size_t)b * O_ + o) * T_ + t;
      #pragma unroll
      for (int r2 = 0; r2 < 4; ++r2)
        po[(size_t)r2 * T_] = (float)acc[mt][nt][r2] * alpha;
    }
  }
}

extern "C" void kernel_launch(void* const* d_in, const int* in_sizes, int n_in,
                              void* d_out, int out_size, void* d_ws, size_t ws_size,
                              hipStream_t stream)
{
  const float* x     = (const float*)d_in[0];
  const float* w     = (const float*)d_in[1];
  const float* gamma = (const float*)d_in[2];
  float* out = (float*)d_out;
  char* ws = (char*)d_ws;
  // ws layout:
  //   [0]       unsigned scale_bits (absmax of normalized x, as float bits)
  //   [16]      double   wsum (sum |w|)
  //   [256]     float    rms[B_*T_]                       (256 KB)
  //   [262400]  int8     wqi[KW][O_][C_]                   (1.84 MB)
  //   [2359552] int8     qa[B_][QT_ROWS][C_]               (33.7 MB)
  unsigned* scale_bits = (unsigned*)ws;
  double*   wsum       = (double*)(ws + 16);
  float*    rms        = (float*)(ws + 256);
  char*     wqi        = (char*)(ws + 262400);
  char*     qa         = (char*)(ws + 2359552);

  hipMemsetAsync(ws, 0, 256, stream);
  k_rms  <<<dim3(B_*T_/256),        256, 0, stream>>>(x, gamma, rms, scale_bits);
  k_wsum <<<dim3(1792),             256, 0, stream>>>(w, wsum, qa);
  k_wq   <<<dim3(O_*C_/256),        256, 0, stream>>>(w, wsum, wqi);
  k_quant<<<dim3(T_/64, C_/64, B_), 256, 0, stream>>>(x, gamma, rms, scale_bits, qa);
  k_conv <<<dim3(T_/NT, O_/MT, B_), 256, 0, stream>>>(wqi, qa, out, scale_bits, wsum);
}

// Round 3
// 503.085 us; speedup vs baseline: 1.1470x; 1.1470x over previous
//
#include <hip/hip_runtime.h>
#include <stdint.h>

#define B_ 8
#define C_ 512
#define O_ 512
#define T_ 8192
#define KW 7
#define NW (O_*C_*KW)          // 1835008 weights
#define QT_ROWS (T_+32)        // qa row j holds t = j-4; rows 0..3 and 8196..8199 zeroed
#define MT 64
#define NT 256
#define BK 64                  // i8 channels per K-tile (64 B rows)
#define BROWS 272              // staged B rows per tile (256 + halo)

typedef __attribute__((ext_vector_type(4))) int i32x4;

// async global->LDS, 16B per lane; LDS dest is wave-uniform base + lane*16
__device__ __forceinline__ void gld16(const void* g, void* l) {
  __builtin_amdgcn_global_load_lds(
      (const __attribute__((address_space(1))) unsigned int*)g,
      (__attribute__((address_space(3))) unsigned int*)l, 16, 0, 0);
}

// ---- K1: per-(b,t) RMS + global absmax of normalized tensor ----------------
// block = 256 t x 512 c (c-split x4 over waves); float4 reads (16 B/lane)
__global__ __launch_bounds__(256) void k_rms(const float* __restrict__ x,
    const float* __restrict__ gamma, float* __restrict__ rms,
    unsigned* __restrict__ scale_bits)
{
  int tid = threadIdx.x, tl = tid & 63, cq = tid >> 6;
  int bt0 = blockIdx.x * 256;               // 256 | 8192 so no b-cross
  int b = bt0 >> 13, t = (bt0 & (T_ - 1)) + tl * 4;
  const float4* px = (const float4*)(x + ((size_t)b * C_ + cq * 128) * T_ + t);
  const float* pg = gamma + cq * 128;       // wave-uniform index -> scalar loads
  float4 ss = {0.f, 0.f, 0.f, 0.f};
  float4 mx = {0.f, 0.f, 0.f, 0.f};
  #pragma unroll 8
  for (int cc = 0; cc < 128; ++cc) {
    float4 v = px[(size_t)cc * (T_ / 4)];   // lanes consecutive -> 1 KB/wave-load
    float g = pg[cc];
    ss.x = fmaf(v.x, v.x, ss.x); ss.y = fmaf(v.y, v.y, ss.y);
    ss.z = fmaf(v.z, v.z, ss.z); ss.w = fmaf(v.w, v.w, ss.w);
    mx.x = fmaxf(mx.x, fabsf(v.x * g)); mx.y = fmaxf(mx.y, fabsf(v.y * g));
    mx.z = fmaxf(mx.z, fabsf(v.z * g)); mx.w = fmaxf(mx.w, fabsf(v.w * g));
  }
  __shared__ float4 s_ss[4][64];
  __shared__ float4 s_m[4][64];
  __shared__ unsigned sm;
  s_ss[cq][tl] = ss; s_m[cq][tl] = mx;
  if (tid == 0) sm = 0u;
  __syncthreads();
  if (cq == 0) {
    float4 a = s_ss[0][tl], b4 = s_ss[1][tl], c4 = s_ss[2][tl], d4 = s_ss[3][tl];
    float4 r;
    r.x = 1.0f / sqrtf((a.x + b4.x + c4.x + d4.x) * (1.0f / 512.0f) + 1e-6f);
    r.y = 1.0f / sqrtf((a.y + b4.y + c4.y + d4.y) * (1.0f / 512.0f) + 1e-6f);
    r.z = 1.0f / sqrtf((a.z + b4.z + c4.z + d4.z) * (1.0f / 512.0f) + 1e-6f);
    r.w = 1.0f / sqrtf((a.w + b4.w + c4.w + d4.w) * (1.0f / 512.0f) + 1e-6f);
    ((float4*)rms)[blockIdx.x * 64 + tl] = r;
    float4 m0 = s_m[0][tl], m1 = s_m[1][tl], m2 = s_m[2][tl], m3 = s_m[3][tl];
    float mm = fmaxf(fmaxf(fmaxf(m0.x, m1.x), fmaxf(m2.x, m3.x)) * r.x,
              fmaxf(fmaxf(fmaxf(m0.y, m1.y), fmaxf(m2.y, m3.y)) * r.y,
              fmaxf(fmaxf(fmaxf(m0.z, m1.z), fmaxf(m2.z, m3.z)) * r.z,
                    fmaxf(fmaxf(m0.w, m1.w), fmaxf(m2.w, m3.w)) * r.w)));
    atomicMax(&sm, __float_as_uint(mm));    // candidates >=0 -> uint order ok
  }
  __syncthreads();
  if (tid == 0) atomicMax(scale_bits, sm);
}

// ---- K2a: sum |w| (+ fused qa halo zeroing in first 32 blocks) -------------
__global__ __launch_bounds__(256) void k_wsum(const float* __restrict__ w,
    double* __restrict__ wsum, char* __restrict__ qa)
{
  int tid = threadIdx.x;
  if (blockIdx.x < 32) {                    // zero t-halo rows of qa (4 B writes)
    int g4 = blockIdx.x * 256 + tid;        // 0..8191 -> 32 KB
    int b = g4 >> 10;
    int idx = (g4 & 1023) * 4;              // byte idx within b's 8 halo rows
    int rr = idx >> 9, c = idx & 511;
    int row = (rr < 4) ? rr : (T_ + rr);    // rows 0..3 and 8196..8199
    *(unsigned*)&qa[((size_t)b * QT_ROWS + row) * C_ + c] = 0u;
  }
  size_t g = (size_t)blockIdx.x * 256 + tid;
  float s = 0.f;
  for (size_t i = g; i < (size_t)NW; i += (size_t)gridDim.x * 256)
    s += fabsf(w[i]);
  __shared__ float red[256];
  red[tid] = s; __syncthreads();
  for (int h = 128; h > 0; h >>= 1) {
    if (tid < h) red[tid] += red[tid + h];
    __syncthreads();
  }
  if (tid == 0) atomicAdd(wsum, (double)red[0]);
}

// ---- K2b: ternary-quantize weights into wqi[k][o][c] (int8 {-1,0,1}) -------
__global__ __launch_bounds__(256) void k_wq(const float* __restrict__ w,
    const double* __restrict__ wsum, char* __restrict__ wqi)
{
  int g = blockIdx.x * 256 + threadIdx.x;   // g = o*C_ + c
  float wsc = fmaxf((float)(*wsum * (1.0 / (double)NW)), 1e-4f);
  const float* pw = w + (size_t)g * KW;
  #pragma unroll
  for (int kk = 0; kk < KW; ++kk) {
    float q = rintf(fminf(fmaxf(pw[kk] / wsc, -1.f), 1.f));
    wqi[(size_t)kk * (O_ * C_) + g] = (char)(int)q;
  }
}

// ---- K3: quantize activations + transpose to qa[b][t+4][c] (int8) ----------
__global__ __launch_bounds__(256) void k_quant(const float* __restrict__ x,
    const float* __restrict__ gamma, const float* __restrict__ rms,
    const unsigned* __restrict__ scale_bits, char* __restrict__ qa)
{
  __shared__ float tile[64][65];            // +1 pad: conflict-free transpose
  int tid = threadIdx.x;
  int tt0 = blockIdx.x * 64;
  int c0  = blockIdx.y * 64;
  int b   = blockIdx.z;
  int tl = tid & 63;
  int q4 = tid >> 6;
  float qmul = 127.0f / fmaxf(__uint_as_float(*scale_bits), 1e-5f);
  const float* px = x + ((size_t)b * C_ + c0) * T_ + tt0;
  float rr = rms[b * T_ + tt0 + tl];
  #pragma unroll
  for (int cc = q4; cc < 64; cc += 4) {     // read coalesced along t
    float v = px[(size_t)cc * T_ + tl];
    float xn = (v * rr) * gamma[c0 + cc];
    tile[cc][tl] = rintf(fminf(fmaxf(xn * qmul, -128.f), 127.f));
  }
  __syncthreads();
  // pack 4 consecutive c into a dword; 4 t-rows per thread
  int c4 = (tid & 15) * 4, tb = tid >> 4;
  char* pq = qa + ((size_t)b * QT_ROWS + (tt0 + 4)) * C_ + c0;
  #pragma unroll
  for (int it = 0; it < 4; ++it) {
    int t2 = tb + it * 16;
    unsigned u = ((unsigned)(unsigned char)(char)(int)tile[c4 + 0][t2])
               | ((unsigned)(unsigned char)(char)(int)tile[c4 + 1][t2] << 8)
               | ((unsigned)(unsigned char)(char)(int)tile[c4 + 2][t2] << 16)
               | ((unsigned)(unsigned char)(char)(int)tile[c4 + 3][t2] << 24);
    *(unsigned*)&pq[(size_t)t2 * C_ + c4] = u;
  }
}

// ---- K4: conv as i8 MFMA GEMM (exact): out = alpha * sum_{k,c} Wk[o,c]*q[c,t+k-3]
// MT=64 x NT=256. v3: fixes v2's vmcnt FIFO hazard —
//   * ALL 28 A fragments (a[7][4], wqi L1/L2-resident, identical across waves)
//     are loaded global->VGPR at the TOP of each c0 iter, BEFORE the B staging
//     gld16s (sched_barrier-pinned). Waiting on a[k] then never drains the
//     staging queue; taps 1..6 run with zero VMEM waits.
//   * B double-buffered in LDS; ONE barrier per iter; its vmcnt(0) drain is the
//     only staging wait and overlaps the other resident block's MFMA phase.
__global__ __launch_bounds__(256, 2) void k_conv(
    const char* __restrict__ wqi,            // [KW][O_][C_] int8
    const char* __restrict__ qa,             // [B_][QT_ROWS][C_] int8 (row = t+4)
    float* __restrict__ out,
    const unsigned* __restrict__ scale_bits,
    const double* __restrict__ wsum)
{
  __shared__ __attribute__((aligned(16))) char lB[2][BROWS * BK];  // 2 x 17 KB
  int tid = threadIdx.x;
  int wave = tid >> 6, lane = tid & 63;
  int quad = lane >> 4, l16 = lane & 15;
  int lrow = lane >> 2;                      // staging: 16 rows x 4 chunks / instr
  int dch = ((lane & 3) - (lane >> 3)) & 3;  // swizzled data chunk for this lane
  int t0 = blockIdx.x * NT;
  int o0 = blockIdx.y * MT;
  int b  = blockIdx.z;

  const char* qa_b = qa + (size_t)b * QT_ROWS * C_;
  // per-lane A base: row (o0+l16), col (quad*16); natural layout (verified v2)
  const char* wA = wqi + (size_t)(o0 + l16) * C_ + quad * 16;

  i32x4 acc[4][4] = {};
  i32x4 a[KW][4];

  // stage B for tile c0: qa rows t0..t0+271 (t = t0-4 .. t0+267); 17 gld16/block
  auto stageB = [&](int c0, char* dst) {
    for (int i = wave; i < 17; i += 4) {
      const char* gB = qa_b + (size_t)(t0 + i * 16 + lrow) * C_ + (c0 + dch * 16);
      gld16(gB, dst + i * 1024 + lane * 16);
    }
  };

  // prologue: stage B(c0=0)
  stageB(0, lB[0]);
  __syncthreads();                           // drains vmcnt: lB[0] ready

  int cur = 0;
  for (int c0 = 0; c0 < C_; c0 += BK) {
    // (1) ALL A loads for this iteration, first in the vmcnt FIFO
    #pragma unroll
    for (int k = 0; k < KW; ++k)
      #pragma unroll
      for (int mt = 0; mt < 4; ++mt)
        a[k][mt] = *(const i32x4*)&wA[(size_t)(k * O_ + mt * 16) * C_ + c0];
    __builtin_amdgcn_sched_barrier(0);       // A-loads strictly before gld16s
    // (2) stage next B tile; stays in flight across the whole MFMA phase
    if (c0 + BK < C_) stageB(c0 + BK, lB[cur ^ 1]);
    __builtin_amdgcn_sched_barrier(0);       // gld16s strictly before k-loop
    const char* rb = lB[cur];
    #pragma unroll
    for (int k = 0; k < KW; ++k) {
      int sft = k + 1;                       // tap shift as LDS row offset
      i32x4 bf[4];
      #pragma unroll
      for (int nt = 0; nt < 4; ++nt) {      // B^T[t][c]: 16 contiguous c per lane
        int r = wave * 64 + nt * 16 + l16 + sft;
        bf[nt] = *(const i32x4*)
            &rb[r * BK + (((quad + (r >> 1)) & 3) * 16)];
      }
      #pragma unroll
      for (int mt = 0; mt < 4; ++mt)
        #pragma unroll
        for (int nt = 0; nt < 4; ++nt)
          acc[mt][nt] = __builtin_amdgcn_mfma_i32_16x16x64_i8(
              a[k][mt], bf[nt], acc[mt][nt], 0, 0, 0);
    }
    __syncthreads();   // waves done reading lB[cur]; lB[cur^1] staging drained
    cur ^= 1;
  }
  // epilogue: dequant scale. C/D layout: col=lane&15, row=quad*4+reg
  float sc  = fmaxf(__uint_as_float(*scale_bits), 1e-5f);
  float wsc = fmaxf((float)(*wsum * (1.0 / (double)NW)), 1e-4f);
  float alpha = sc * (1.0f / 127.0f) * wsc;
  #pragma unroll
  for (int mt = 0; mt < 4; ++mt) {
    int o = o0 + mt * 16 + quad * 4;
    #pragma unroll
    for (int nt = 0; nt < 4; ++nt) {
      int t = t0 + wave * 64 + nt * 16 + l16;
      float* po = out + ((size_t)b * O_ + o) * T_ + t;
      #pragma unroll
      for (int r2 = 0; r2 < 4; ++r2)
        po[(size_t)r2 * T_] = (float)acc[mt][nt][r2] * alpha;
    }
  }
}

extern "C" void kernel_launch(void* const* d_in, const int* in_sizes, int n_in,
                              void* d_out, int out_size, void* d_ws, size_t ws_size,
                              hipStream_t stream)
{
  const float* x     = (const float*)d_in[0];
  const float* w     = (const float*)d_in[1];
  const float* gamma = (const float*)d_in[2];
  float* out = (float*)d_out;
  char* ws = (char*)d_ws;
  // ws layout:
  //   [0]       unsigned scale_bits (absmax of normalized x, as float bits)
  //   [16]      double   wsum (sum |w|)
  //   [256]     float    rms[B_*T_]                       (256 KB)
  //   [262400]  int8     wqi[KW][O_][C_]                   (1.84 MB)
  //   [2359552] int8     qa[B_][QT_ROWS][C_]               (33.7 MB)
  unsigned* scale_bits = (unsigned*)ws;
  double*   wsum       = (double*)(ws + 16);
  float*    rms        = (float*)(ws + 256);
  char*     wqi        = (char*)(ws + 262400);
  char*     qa         = (char*)(ws + 2359552);

  hipMemsetAsync(ws, 0, 256, stream);
  k_rms  <<<dim3(B_*T_/256),        256, 0, stream>>>(x, gamma, rms, scale_bits);
  k_wsum <<<dim3(1792),             256, 0, stream>>>(w, wsum, qa);
  k_wq   <<<dim3(O_*C_/256),        256, 0, stream>>>(w, wsum, wqi);
  k_quant<<<dim3(T_/64, C_/64, B_), 256, 0, stream>>>(x, gamma, rms, scale_bits, qa);
  k_conv <<<dim3(T_/NT, O_/MT, B_), 256, 0, stream>>>(wqi, qa, out, scale_bits, wsum);
}

// Round 4
// 368.366 us; speedup vs baseline: 1.5665x; 1.3657x over previous
//
#include <hip/hip_runtime.h>
#include <stdint.h>

#define B_ 8
#define C_ 512
#define O_ 512
#define T_ 8192
#define KW 7
#define NW (O_*C_*KW)          // 1835008 weights
#define QT_ROWS (T_+32)        // qa row j holds t = j-4; rows 0..3 and 8196..8199 zeroed
#define MT 64
#define NT 256
#define BK 64                  // i8 channels per K-tile (64 B rows)
#define BROWS 272              // staged B rows per tile (256 + halo)

typedef __attribute__((ext_vector_type(4))) int i32x4;

// async global->LDS, 16B per lane; LDS dest is wave-uniform base + lane*16
__device__ __forceinline__ void gld16(const void* g, void* l) {
  __builtin_amdgcn_global_load_lds(
      (const __attribute__((address_space(1))) unsigned int*)g,
      (__attribute__((address_space(3))) unsigned int*)l, 16, 0, 0);
}

// ---- K1: per-(b,t) RMS + global absmax of normalized tensor ----------------
// block = 256 t x 512 c (c-split x4 over waves); float4 reads (16 B/lane)
__global__ __launch_bounds__(256) void k_rms(const float* __restrict__ x,
    const float* __restrict__ gamma, float* __restrict__ rms,
    unsigned* __restrict__ scale_bits)
{
  int tid = threadIdx.x, tl = tid & 63, cq = tid >> 6;
  int bt0 = blockIdx.x * 256;               // 256 | 8192 so no b-cross
  int b = bt0 >> 13, t = (bt0 & (T_ - 1)) + tl * 4;
  const float4* px = (const float4*)(x + ((size_t)b * C_ + cq * 128) * T_ + t);
  const float* pg = gamma + cq * 128;       // wave-uniform index -> scalar loads
  float4 ss = {0.f, 0.f, 0.f, 0.f};
  float4 mx = {0.f, 0.f, 0.f, 0.f};
  #pragma unroll 8
  for (int cc = 0; cc < 128; ++cc) {
    float4 v = px[(size_t)cc * (T_ / 4)];   // lanes consecutive -> 1 KB/wave-load
    float g = pg[cc];
    ss.x = fmaf(v.x, v.x, ss.x); ss.y = fmaf(v.y, v.y, ss.y);
    ss.z = fmaf(v.z, v.z, ss.z); ss.w = fmaf(v.w, v.w, ss.w);
    mx.x = fmaxf(mx.x, fabsf(v.x * g)); mx.y = fmaxf(mx.y, fabsf(v.y * g));
    mx.z = fmaxf(mx.z, fabsf(v.z * g)); mx.w = fmaxf(mx.w, fabsf(v.w * g));
  }
  __shared__ float4 s_ss[4][64];
  __shared__ float4 s_m[4][64];
  __shared__ unsigned sm;
  s_ss[cq][tl] = ss; s_m[cq][tl] = mx;
  if (tid == 0) sm = 0u;
  __syncthreads();
  if (cq == 0) {
    float4 a = s_ss[0][tl], b4 = s_ss[1][tl], c4 = s_ss[2][tl], d4 = s_ss[3][tl];
    float4 r;
    r.x = 1.0f / sqrtf((a.x + b4.x + c4.x + d4.x) * (1.0f / 512.0f) + 1e-6f);
    r.y = 1.0f / sqrtf((a.y + b4.y + c4.y + d4.y) * (1.0f / 512.0f) + 1e-6f);
    r.z = 1.0f / sqrtf((a.z + b4.z + c4.z + d4.z) * (1.0f / 512.0f) + 1e-6f);
    r.w = 1.0f / sqrtf((a.w + b4.w + c4.w + d4.w) * (1.0f / 512.0f) + 1e-6f);
    ((float4*)rms)[blockIdx.x * 64 + tl] = r;
    float4 m0 = s_m[0][tl], m1 = s_m[1][tl], m2 = s_m[2][tl], m3 = s_m[3][tl];
    float mm = fmaxf(fmaxf(fmaxf(m0.x, m1.x), fmaxf(m2.x, m3.x)) * r.x,
              fmaxf(fmaxf(fmaxf(m0.y, m1.y), fmaxf(m2.y, m3.y)) * r.y,
              fmaxf(fmaxf(fmaxf(m0.z, m1.z), fmaxf(m2.z, m3.z)) * r.z,
                    fmaxf(fmaxf(m0.w, m1.w), fmaxf(m2.w, m3.w)) * r.w)));
    atomicMax(&sm, __float_as_uint(mm));    // candidates >=0 -> uint order ok
  }
  __syncthreads();
  if (tid == 0) atomicMax(scale_bits, sm);
}

// ---- K2a: sum |w| (+ fused qa halo zeroing in first 32 blocks) -------------
__global__ __launch_bounds__(256) void k_wsum(const float* __restrict__ w,
    double* __restrict__ wsum, char* __restrict__ qa)
{
  int tid = threadIdx.x;
  if (blockIdx.x < 32) {                    // zero t-halo rows of qa (4 B writes)
    int g4 = blockIdx.x * 256 + tid;        // 0..8191 -> 32 KB
    int b = g4 >> 10;
    int idx = (g4 & 1023) * 4;              // byte idx within b's 8 halo rows
    int rr = idx >> 9, c = idx & 511;
    int row = (rr < 4) ? rr : (T_ + rr);    // rows 0..3 and 8196..8199
    *(unsigned*)&qa[((size_t)b * QT_ROWS + row) * C_ + c] = 0u;
  }
  size_t g = (size_t)blockIdx.x * 256 + tid;
  float s = 0.f;
  for (size_t i = g; i < (size_t)NW; i += (size_t)gridDim.x * 256)
    s += fabsf(w[i]);
  __shared__ float red[256];
  red[tid] = s; __syncthreads();
  for (int h = 128; h > 0; h >>= 1) {
    if (tid < h) red[tid] += red[tid + h];
    __syncthreads();
  }
  if (tid == 0) atomicAdd(wsum, (double)red[0]);
}

// ---- K2b: ternary-quantize weights into wqi[k][o][c] (int8 {-1,0,1}) -------
__global__ __launch_bounds__(256) void k_wq(const float* __restrict__ w,
    const double* __restrict__ wsum, char* __restrict__ wqi)
{
  int g = blockIdx.x * 256 + threadIdx.x;   // g = o*C_ + c
  float wsc = fmaxf((float)(*wsum * (1.0 / (double)NW)), 1e-4f);
  const float* pw = w + (size_t)g * KW;
  #pragma unroll
  for (int kk = 0; kk < KW; ++kk) {
    float q = rintf(fminf(fmaxf(pw[kk] / wsc, -1.f), 1.f));
    wqi[(size_t)kk * (O_ * C_) + g] = (char)(int)q;
  }
}

// ---- K3: quantize activations + transpose to qa[b][t+4][c] (int8) ----------
// v4: vectorized — float4 loads (16 B/lane) and uint4 stores (16 B/lane).
__global__ __launch_bounds__(256) void k_quant(const float* __restrict__ x,
    const float* __restrict__ gamma, const float* __restrict__ rms,
    const unsigned* __restrict__ scale_bits, char* __restrict__ qa)
{
  __shared__ float tile[64][65];            // +1 pad: conflict-free transpose
  int tid = threadIdx.x;
  int tt0 = blockIdx.x * 64;
  int c0  = blockIdx.y * 64;
  int b   = blockIdx.z;
  float qmul = 127.0f / fmaxf(__uint_as_float(*scale_bits), 1e-5f);
  int t4 = (tid & 15) * 4;                  // 4 consecutive t per thread
  const float* px = x + ((size_t)b * C_ + c0) * T_ + tt0;
  float4 rr = *(const float4*)(rms + (size_t)b * T_ + tt0 + t4);
  #pragma unroll
  for (int p = 0; p < 4; ++p) {
    int cc = (tid >> 4) + p * 16;           // 16 c-rows per pass
    float4 v = *(const float4*)(px + (size_t)cc * T_ + t4);
    float g = gamma[c0 + cc];
    tile[cc][t4 + 0] = rintf(fminf(fmaxf(((v.x * rr.x) * g) * qmul, -128.f), 127.f));
    tile[cc][t4 + 1] = rintf(fminf(fmaxf(((v.y * rr.y) * g) * qmul, -128.f), 127.f));
    tile[cc][t4 + 2] = rintf(fminf(fmaxf(((v.z * rr.z) * g) * qmul, -128.f), 127.f));
    tile[cc][t4 + 3] = rintf(fminf(fmaxf(((v.w * rr.w) * g) * qmul, -128.f), 127.f));
  }
  __syncthreads();
  // pack 16 consecutive c into one uint4; one t-row per thread
  int c16 = (tid & 3) * 16, t2 = tid >> 2;  // t2 = 0..63
  unsigned u[4];
  #pragma unroll
  for (int d = 0; d < 4; ++d)
    u[d] = ((unsigned)(unsigned char)(char)(int)tile[c16 + d * 4 + 0][t2])
         | ((unsigned)(unsigned char)(char)(int)tile[c16 + d * 4 + 1][t2] << 8)
         | ((unsigned)(unsigned char)(char)(int)tile[c16 + d * 4 + 2][t2] << 16)
         | ((unsigned)(unsigned char)(char)(int)tile[c16 + d * 4 + 3][t2] << 24);
  char* pq = qa + ((size_t)b * QT_ROWS + (tt0 + 4 + t2)) * C_ + c0 + c16;
  *(uint4*)pq = make_uint4(u[0], u[1], u[2], u[3]);
}

// ---- K4: conv as i8 MFMA GEMM (exact): out = alpha * sum_{k,c} Wk[o,c]*q[c,t+k-3]
// MT=64 x NT=256; all 7 taps staged; K=64 per MFMA; swizzled LDS (0 conflicts).
// v4 = v1 structure (empirically fastest: A+B in LDS, 2 barriers, 3 blocks/CU)
//      + s_setprio(1) around each 16-MFMA cluster (T5; blocks not lockstep).
__global__ __launch_bounds__(256, 3) void k_conv(
    const char* __restrict__ wqi,            // [KW][O_][C_] int8
    const char* __restrict__ qa,             // [B_][QT_ROWS][C_] int8 (row = t+4)
    float* __restrict__ out,
    const unsigned* __restrict__ scale_bits,
    const double* __restrict__ wsum)
{
  __shared__ __attribute__((aligned(16))) char lA[KW * 64 * BK];  // 28 KB
  __shared__ __attribute__((aligned(16))) char lB[BROWS * BK];    // 17 KB
  int tid = threadIdx.x;
  int wave = tid >> 6, lane = tid & 63;
  int quad = lane >> 4, l16 = lane & 15;
  int lrow = lane >> 2;                      // staging: 16 rows x 4 chunks / instr
  int dch = ((lane & 3) - (lane >> 3)) & 3;  // swizzled data chunk for this lane
  int t0 = blockIdx.x * NT;
  int o0 = blockIdx.y * MT;
  int b  = blockIdx.z;

  const char* qa_b = qa + (size_t)b * QT_ROWS * C_;

  i32x4 acc[4][4] = {};

  for (int c0 = 0; c0 < C_; c0 += BK) {
    // stage B: qa rows t0..t0+271 (t = t0-4 .. t0+267), 64 c; 17 instrs
    for (int i = wave; i < 17; i += 4) {
      const char* gB = qa_b + (size_t)(t0 + i * 16 + lrow) * C_ + (c0 + dch * 16);
      gld16(gB, &lB[i * 1024 + lane * 16]);
    }
    // stage A: all 7 taps, 64 o-rows x 64 c each; 28 instrs
    for (int i = wave; i < 28; i += 4) {
      int k = i >> 2, ii = i & 3;
      const char* gA =
          wqi + (size_t)(k * O_ + o0 + ii * 16 + lrow) * C_ + (c0 + dch * 16);
      gld16(gA, &lA[i * 1024 + lane * 16]);
    }
    __syncthreads();
    #pragma unroll
    for (int k = 0; k < KW; ++k) {
      i32x4 af[4], bf[4];
      #pragma unroll
      for (int mt = 0; mt < 4; ++mt) {      // A[m=lane&15][k8=quad*16+j]
        int r = mt * 16 + l16;
        af[mt] = *(const i32x4*)
            &lA[k * 4096 + r * BK + (((quad + (r >> 1)) & 3) * 16)];
      }
      int sft = k + 1;                       // tap shift as LDS row offset
      #pragma unroll
      for (int nt = 0; nt < 4; ++nt) {      // B^T[t][c]: 16 contiguous c per lane
        int r = wave * 64 + nt * 16 + l16 + sft;
        bf[nt] = *(const i32x4*)
            &lB[r * BK + (((quad + (r >> 1)) & 3) * 16)];
      }
      __builtin_amdgcn_s_setprio(1);
      #pragma unroll
      for (int mt = 0; mt < 4; ++mt)
        #pragma unroll
        for (int nt = 0; nt < 4; ++nt)
          acc[mt][nt] = __builtin_amdgcn_mfma_i32_16x16x64_i8(
              af[mt], bf[nt], acc[mt][nt], 0, 0, 0);
      __builtin_amdgcn_s_setprio(0);
    }
    __syncthreads();
  }
  // epilogue: dequant scale. C/D layout: col=lane&15, row=quad*4+reg
  float sc  = fmaxf(__uint_as_float(*scale_bits), 1e-5f);
  float wsc = fmaxf((float)(*wsum * (1.0 / (double)NW)), 1e-4f);
  float alpha = sc * (1.0f / 127.0f) * wsc;
  #pragma unroll
  for (int mt = 0; mt < 4; ++mt) {
    int o = o0 + mt * 16 + quad * 4;
    #pragma unroll
    for (int nt = 0; nt < 4; ++nt) {
      int t = t0 + wave * 64 + nt * 16 + l16;
      float* po = out + ((size_t)b * O_ + o) * T_ + t;
      #pragma unroll
      for (int r2 = 0; r2 < 4; ++r2)
        po[(size_t)r2 * T_] = (float)acc[mt][nt][r2] * alpha;
    }
  }
}

extern "C" void kernel_launch(void* const* d_in, const int* in_sizes, int n_in,
                              void* d_out, int out_size, void* d_ws, size_t ws_size,
                              hipStream_t stream)
{
  const float* x     = (const float*)d_in[0];
  const float* w     = (const float*)d_in[1];
  const float* gamma = (const float*)d_in[2];
  float* out = (float*)d_out;
  char* ws = (char*)d_ws;
  // ws layout:
  //   [0]       unsigned scale_bits (absmax of normalized x, as float bits)
  //   [16]      double   wsum (sum |w|)
  //   [256]     float    rms[B_*T_]                       (256 KB)
  //   [262400]  int8     wqi[KW][O_][C_]                   (1.84 MB)
  //   [2359552] int8     qa[B_][QT_ROWS][C_]               (33.7 MB)
  unsigned* scale_bits = (unsigned*)ws;
  double*   wsum       = (double*)(ws + 16);
  float*    rms        = (float*)(ws + 256);
  char*     wqi        = (char*)(ws + 262400);
  char*     qa         = (char*)(ws + 2359552);

  hipMemsetAsync(ws, 0, 256, stream);
  k_rms  <<<dim3(B_*T_/256),        256, 0, stream>>>(x, gamma, rms, scale_bits);
  k_wsum <<<dim3(1792),             256, 0, stream>>>(w, wsum, qa);
  k_wq   <<<dim3(O_*C_/256),        256, 0, stream>>>(w, wsum, wqi);
  k_quant<<<dim3(T_/64, C_/64, B_), 256, 0, stream>>>(x, gamma, rms, scale_bits, qa);
  k_conv <<<dim3(T_/NT, O_/MT, B_), 256, 0, stream>>>(wqi, qa, out, scale_bits, wsum);
}

// Round 5
// 349.076 us; speedup vs baseline: 1.6531x; 1.0553x over previous
//
#include <hip/hip_runtime.h>
#include <stdint.h>

#define B_ 8
#define C_ 512
#define O_ 512
#define T_ 8192
#define KW 7
#define NW (O_*C_*KW)          // 1835008 weights
#define QT_ROWS (T_+32)        // qa row j holds t = j-4; rows 0..3 and 8196..8199 zeroed
#define MT 64
#define NT 256
#define BK 64                  // i8 channels per K-tile (64 B rows)
#define BROWS 272              // staged B rows per tile (256 + halo)
#define WSUM_BLKS 1792

typedef __attribute__((ext_vector_type(4))) int i32x4;

// async global->LDS, 16B per lane; LDS dest is wave-uniform base + lane*16
__device__ __forceinline__ void gld16(const void* g, void* l) {
  __builtin_amdgcn_global_load_lds(
      (const __attribute__((address_space(1))) unsigned int*)g,
      (__attribute__((address_space(3))) unsigned int*)l, 16, 0, 0);
}

// ---- K1: per-(b,t) RMS + per-block absmax of normalized tensor -------------
// v5: NO global atomic — block max written to smax[blockIdx.x] (k_red reduces).
__global__ __launch_bounds__(256) void k_rms(const float* __restrict__ x,
    const float* __restrict__ gamma, float* __restrict__ rms,
    unsigned* __restrict__ smax)
{
  int tid = threadIdx.x, tl = tid & 63, cq = tid >> 6;
  int bt0 = blockIdx.x * 256;               // 256 | 8192 so no b-cross
  int b = bt0 >> 13, t = (bt0 & (T_ - 1)) + tl * 4;
  const float4* px = (const float4*)(x + ((size_t)b * C_ + cq * 128) * T_ + t);
  const float* pg = gamma + cq * 128;       // wave-uniform index -> scalar loads
  float4 ss = {0.f, 0.f, 0.f, 0.f};
  float4 mx = {0.f, 0.f, 0.f, 0.f};
  #pragma unroll 8
  for (int cc = 0; cc < 128; ++cc) {
    float4 v = px[(size_t)cc * (T_ / 4)];   // lanes consecutive -> 1 KB/wave-load
    float g = pg[cc];
    ss.x = fmaf(v.x, v.x, ss.x); ss.y = fmaf(v.y, v.y, ss.y);
    ss.z = fmaf(v.z, v.z, ss.z); ss.w = fmaf(v.w, v.w, ss.w);
    mx.x = fmaxf(mx.x, fabsf(v.x * g)); mx.y = fmaxf(mx.y, fabsf(v.y * g));
    mx.z = fmaxf(mx.z, fabsf(v.z * g)); mx.w = fmaxf(mx.w, fabsf(v.w * g));
  }
  __shared__ float4 s_ss[4][64];
  __shared__ float4 s_m[4][64];
  __shared__ unsigned sm;
  s_ss[cq][tl] = ss; s_m[cq][tl] = mx;
  if (tid == 0) sm = 0u;
  __syncthreads();
  if (cq == 0) {
    float4 a = s_ss[0][tl], b4 = s_ss[1][tl], c4 = s_ss[2][tl], d4 = s_ss[3][tl];
    float4 r;
    r.x = 1.0f / sqrtf((a.x + b4.x + c4.x + d4.x) * (1.0f / 512.0f) + 1e-6f);
    r.y = 1.0f / sqrtf((a.y + b4.y + c4.y + d4.y) * (1.0f / 512.0f) + 1e-6f);
    r.z = 1.0f / sqrtf((a.z + b4.z + c4.z + d4.z) * (1.0f / 512.0f) + 1e-6f);
    r.w = 1.0f / sqrtf((a.w + b4.w + c4.w + d4.w) * (1.0f / 512.0f) + 1e-6f);
    ((float4*)rms)[blockIdx.x * 64 + tl] = r;
    float4 m0 = s_m[0][tl], m1 = s_m[1][tl], m2 = s_m[2][tl], m3 = s_m[3][tl];
    float mm = fmaxf(fmaxf(fmaxf(m0.x, m1.x), fmaxf(m2.x, m3.x)) * r.x,
              fmaxf(fmaxf(fmaxf(m0.y, m1.y), fmaxf(m2.y, m3.y)) * r.y,
              fmaxf(fmaxf(fmaxf(m0.z, m1.z), fmaxf(m2.z, m3.z)) * r.z,
                    fmaxf(fmaxf(m0.w, m1.w), fmaxf(m2.w, m3.w)) * r.w)));
    atomicMax(&sm, __float_as_uint(mm));    // shared-mem atomic: cheap
  }
  __syncthreads();
  if (tid == 0) smax[blockIdx.x] = sm;      // no global atomic
}

// ---- K2a: sum |w| partials (+ fused qa halo zeroing in first 32 blocks) ----
// v5: NO global atomic — per-block partial to wpart[blockIdx.x].
__global__ __launch_bounds__(256) void k_wsum(const float* __restrict__ w,
    float* __restrict__ wpart, char* __restrict__ qa)
{
  int tid = threadIdx.x;
  if (blockIdx.x < 32) {                    // zero t-halo rows of qa (4 B writes)
    int g4 = blockIdx.x * 256 + tid;        // 0..8191 -> 32 KB
    int b = g4 >> 10;
    int idx = (g4 & 1023) * 4;              // byte idx within b's 8 halo rows
    int rr = idx >> 9, c = idx & 511;
    int row = (rr < 4) ? rr : (T_ + rr);    // rows 0..3 and 8196..8199
    *(unsigned*)&qa[((size_t)b * QT_ROWS + row) * C_ + c] = 0u;
  }
  size_t g = (size_t)blockIdx.x * 256 + tid;
  float s = 0.f;
  for (size_t i = g; i < (size_t)NW; i += (size_t)gridDim.x * 256)
    s += fabsf(w[i]);
  __shared__ float red[256];
  red[tid] = s; __syncthreads();
  for (int h = 128; h > 0; h >>= 1) {
    if (tid < h) red[tid] += red[tid + h];
    __syncthreads();
  }
  if (tid == 0) wpart[blockIdx.x] = red[0]; // no global atomic
}

// ---- K2r: single-block reduce: wpart[1792] -> wsum; smax[256] -> scale_bits
__global__ __launch_bounds__(256) void k_red(const float* __restrict__ wpart,
    const unsigned* __restrict__ smax, double* __restrict__ wsum,
    unsigned* __restrict__ scale_bits)
{
  int tid = threadIdx.x;
  double s = 0.0;
  for (int i = tid; i < WSUM_BLKS; i += 256) s += (double)wpart[i];
  unsigned m = smax[tid];                   // 256 entries, 1/thread
  __shared__ double sd[256];
  __shared__ unsigned su[256];
  sd[tid] = s; su[tid] = m; __syncthreads();
  for (int h = 128; h > 0; h >>= 1) {
    if (tid < h) { sd[tid] += sd[tid + h]; su[tid] = max(su[tid], su[tid + h]); }
    __syncthreads();
  }
  if (tid == 0) { *wsum = sd[0]; *scale_bits = su[0]; }
}

// ---- K2b: ternary-quantize weights into wqi[k][o][c] (int8 {-1,0,1}) -------
__global__ __launch_bounds__(256) void k_wq(const float* __restrict__ w,
    const double* __restrict__ wsum, char* __restrict__ wqi)
{
  int g = blockIdx.x * 256 + threadIdx.x;   // g = o*C_ + c
  float wsc = fmaxf((float)(*wsum * (1.0 / (double)NW)), 1e-4f);
  const float* pw = w + (size_t)g * KW;
  #pragma unroll
  for (int kk = 0; kk < KW; ++kk) {
    float q = rintf(fminf(fmaxf(pw[kk] / wsc, -1.f), 1.f));
    wqi[(size_t)kk * (O_ * C_) + g] = (char)(int)q;
  }
}

// ---- K3: quantize activations + transpose to qa[b][t+4][c] (int8) ----------
// vectorized — float4 loads (16 B/lane) and uint4 stores (16 B/lane).
__global__ __launch_bounds__(256) void k_quant(const float* __restrict__ x,
    const float* __restrict__ gamma, const float* __restrict__ rms,
    const unsigned* __restrict__ scale_bits, char* __restrict__ qa)
{
  __shared__ float tile[64][65];            // +1 pad: conflict-free transpose
  int tid = threadIdx.x;
  int tt0 = blockIdx.x * 64;
  int c0  = blockIdx.y * 64;
  int b   = blockIdx.z;
  float qmul = 127.0f / fmaxf(__uint_as_float(*scale_bits), 1e-5f);
  int t4 = (tid & 15) * 4;                  // 4 consecutive t per thread
  const float* px = x + ((size_t)b * C_ + c0) * T_ + tt0;
  float4 rr = *(const float4*)(rms + (size_t)b * T_ + tt0 + t4);
  #pragma unroll
  for (int p = 0; p < 4; ++p) {
    int cc = (tid >> 4) + p * 16;           // 16 c-rows per pass
    float4 v = *(const float4*)(px + (size_t)cc * T_ + t4);
    float g = gamma[c0 + cc];
    tile[cc][t4 + 0] = rintf(fminf(fmaxf(((v.x * rr.x) * g) * qmul, -128.f), 127.f));
    tile[cc][t4 + 1] = rintf(fminf(fmaxf(((v.y * rr.y) * g) * qmul, -128.f), 127.f));
    tile[cc][t4 + 2] = rintf(fminf(fmaxf(((v.z * rr.z) * g) * qmul, -128.f), 127.f));
    tile[cc][t4 + 3] = rintf(fminf(fmaxf(((v.w * rr.w) * g) * qmul, -128.f), 127.f));
  }
  __syncthreads();
  // pack 16 consecutive c into one uint4; one t-row per thread
  int c16 = (tid & 3) * 16, t2 = tid >> 2;  // t2 = 0..63
  unsigned u[4];
  #pragma unroll
  for (int d = 0; d < 4; ++d)
    u[d] = ((unsigned)(unsigned char)(char)(int)tile[c16 + d * 4 + 0][t2])
         | ((unsigned)(unsigned char)(char)(int)tile[c16 + d * 4 + 1][t2] << 8)
         | ((unsigned)(unsigned char)(char)(int)tile[c16 + d * 4 + 2][t2] << 16)
         | ((unsigned)(unsigned char)(char)(int)tile[c16 + d * 4 + 3][t2] << 24);
  char* pq = qa + ((size_t)b * QT_ROWS + (tt0 + 4 + t2)) * C_ + c0 + c16;
  *(uint4*)pq = make_uint4(u[0], u[1], u[2], u[3]);
}

// ---- K4: conv as i8 MFMA GEMM (exact): out = alpha * sum_{k,c} Wk[o,c]*q[c,t+k-3]
// MT=64 x NT=256; all 7 taps staged; K=64 per MFMA; swizzled LDS (0 conflicts).
// v1 structure (A+B in LDS, 2 barriers, 3 blocks/CU) + s_setprio around MFMAs.
// Measured r4: 104 us, MfmaUtil 54.6%, 0 bank conflicts. Do not restructure
// without within-probe A/B (v2/v3 register-pipeline rewrites both regressed).
__global__ __launch_bounds__(256, 3) void k_conv(
    const char* __restrict__ wqi,            // [KW][O_][C_] int8
    const char* __restrict__ qa,             // [B_][QT_ROWS][C_] int8 (row = t+4)
    float* __restrict__ out,
    const unsigned* __restrict__ scale_bits,
    const double* __restrict__ wsum)
{
  __shared__ __attribute__((aligned(16))) char lA[KW * 64 * BK];  // 28 KB
  __shared__ __attribute__((aligned(16))) char lB[BROWS * BK];    // 17 KB
  int tid = threadIdx.x;
  int wave = tid >> 6, lane = tid & 63;
  int quad = lane >> 4, l16 = lane & 15;
  int lrow = lane >> 2;                      // staging: 16 rows x 4 chunks / instr
  int dch = ((lane & 3) - (lane >> 3)) & 3;  // swizzled data chunk for this lane
  int t0 = blockIdx.x * NT;
  int o0 = blockIdx.y * MT;
  int b  = blockIdx.z;

  const char* qa_b = qa + (size_t)b * QT_ROWS * C_;

  i32x4 acc[4][4] = {};

  for (int c0 = 0; c0 < C_; c0 += BK) {
    // stage B: qa rows t0..t0+271 (t = t0-4 .. t0+267), 64 c; 17 instrs
    for (int i = wave; i < 17; i += 4) {
      const char* gB = qa_b + (size_t)(t0 + i * 16 + lrow) * C_ + (c0 + dch * 16);
      gld16(gB, &lB[i * 1024 + lane * 16]);
    }
    // stage A: all 7 taps, 64 o-rows x 64 c each; 28 instrs
    for (int i = wave; i < 28; i += 4) {
      int k = i >> 2, ii = i & 3;
      const char* gA =
          wqi + (size_t)(k * O_ + o0 + ii * 16 + lrow) * C_ + (c0 + dch * 16);
      gld16(gA, &lA[i * 1024 + lane * 16]);
    }
    __syncthreads();
    #pragma unroll
    for (int k = 0; k < KW; ++k) {
      i32x4 af[4], bf[4];
      #pragma unroll
      for (int mt = 0; mt < 4; ++mt) {      // A[m=lane&15][k8=quad*16+j]
        int r = mt * 16 + l16;
        af[mt] = *(const i32x4*)
            &lA[k * 4096 + r * BK + (((quad + (r >> 1)) & 3) * 16)];
      }
      int sft = k + 1;                       // tap shift as LDS row offset
      #pragma unroll
      for (int nt = 0; nt < 4; ++nt) {      // B^T[t][c]: 16 contiguous c per lane
        int r = wave * 64 + nt * 16 + l16 + sft;
        bf[nt] = *(const i32x4*)
            &lB[r * BK + (((quad + (r >> 1)) & 3) * 16)];
      }
      __builtin_amdgcn_s_setprio(1);
      #pragma unroll
      for (int mt = 0; mt < 4; ++mt)
        #pragma unroll
        for (int nt = 0; nt < 4; ++nt)
          acc[mt][nt] = __builtin_amdgcn_mfma_i32_16x16x64_i8(
              af[mt], bf[nt], acc[mt][nt], 0, 0, 0);
      __builtin_amdgcn_s_setprio(0);
    }
    __syncthreads();
  }
  // epilogue: dequant scale. C/D layout: col=lane&15, row=quad*4+reg
  float sc  = fmaxf(__uint_as_float(*scale_bits), 1e-5f);
  float wsc = fmaxf((float)(*wsum * (1.0 / (double)NW)), 1e-4f);
  float alpha = sc * (1.0f / 127.0f) * wsc;
  #pragma unroll
  for (int mt = 0; mt < 4; ++mt) {
    int o = o0 + mt * 16 + quad * 4;
    #pragma unroll
    for (int nt = 0; nt < 4; ++nt) {
      int t = t0 + wave * 64 + nt * 16 + l16;
      float* po = out + ((size_t)b * O_ + o) * T_ + t;
      #pragma unroll
      for (int r2 = 0; r2 < 4; ++r2)
        po[(size_t)r2 * T_] = (float)acc[mt][nt][r2] * alpha;
    }
  }
}

extern "C" void kernel_launch(void* const* d_in, const int* in_sizes, int n_in,
                              void* d_out, int out_size, void* d_ws, size_t ws_size,
                              hipStream_t stream)
{
  const float* x     = (const float*)d_in[0];
  const float* w     = (const float*)d_in[1];
  const float* gamma = (const float*)d_in[2];
  float* out = (float*)d_out;
  char* ws = (char*)d_ws;
  // ws layout:
  //   [0]       unsigned scale_bits (absmax of normalized x, as float bits)
  //   [16]      double   wsum (sum |w|)
  //   [256]     float    rms[B_*T_]                       (256 KB)
  //   [262400]  int8     wqi[KW][O_][C_]                   (1.84 MB)
  //     NOTE: wqi[0..7167] transiently holds wpart[1792] (float) and
  //     wqi[8192..9215] holds smax[256] (u32); both are produced by
  //     k_wsum/k_rms and consumed by k_red BEFORE k_wq overwrites wqi.
  //   [2359552] int8     qa[B_][QT_ROWS][C_]               (33.7 MB)
  unsigned* scale_bits = (unsigned*)ws;
  double*   wsum       = (double*)(ws + 16);
  float*    rms        = (float*)(ws + 256);
  char*     wqi        = (char*)(ws + 262400);
  float*    wpart      = (float*)(ws + 262400);
  unsigned* smax       = (unsigned*)(ws + 262400 + 8192);
  char*     qa         = (char*)(ws + 2359552);

  hipMemsetAsync(ws, 0, 256, stream);
  k_rms  <<<dim3(B_*T_/256),        256, 0, stream>>>(x, gamma, rms, smax);
  k_wsum <<<dim3(WSUM_BLKS),        256, 0, stream>>>(w, wpart, qa);
  k_red  <<<dim3(1),                256, 0, stream>>>(wpart, smax, wsum, scale_bits);
  k_wq   <<<dim3(O_*C_/256),        256, 0, stream>>>(w, wsum, wqi);
  k_quant<<<dim3(T_/64, C_/64, B_), 256, 0, stream>>>(x, gamma, rms, scale_bits, qa);
  k_conv <<<dim3(T_/NT, O_/MT, B_), 256, 0, stream>>>(wqi, qa, out, scale_bits, wsum);
}